// Round 4
// baseline (1095.861 us; speedup 1.0000x reference)
//
#include <hip/hip_runtime.h>
#include <math.h>

#define NN_   6000
#define EE_   192000
#define CIN_  32
#define CHID_ 64
#define KK_   125   // 5^3 spline kernel cells
#define SS_   8     // 2^3 corners
#define EB_   64    // edge batch per block in build_T

// fp32 -> bf16 round-to-nearest-even
static __device__ __forceinline__ unsigned short f2bf(float f) {
    unsigned int u = __builtin_bit_cast(unsigned int, f);
    u += 0x7fff + ((u >> 16) & 1);
    return (unsigned short)(u >> 16);
}

// ---------------------------------------------------------------------------
// Bucketing: counting sort of edges by dst.
// ---------------------------------------------------------------------------
__global__ __launch_bounds__(256) void count_deg_kernel(
    const int* __restrict__ ei, int* __restrict__ deg)
{
    int e = blockIdx.x * 256 + threadIdx.x;
    if (e < EE_) atomicAdd(&deg[ei[EE_ + e]], 1);
}

__global__ __launch_bounds__(1024) void scan_kernel(
    const int* __restrict__ deg, int* __restrict__ offs, int* __restrict__ cursor)
{
    __shared__ int part[1024];
    const int tid = threadIdx.x;
    const int CH = (NN_ + 1023) / 1024;   // 6
    const int base = tid * CH;
    int loc[CH];
    int s = 0;
#pragma unroll
    for (int i = 0; i < CH; ++i) {
        int v = (base + i < NN_) ? deg[base + i] : 0;
        loc[i] = s; s += v;
    }
    part[tid] = s;
    __syncthreads();
    for (int off = 1; off < 1024; off <<= 1) {
        int v = (tid >= off) ? part[tid - off] : 0;
        __syncthreads();
        part[tid] += v;
        __syncthreads();
    }
    const int pre = (tid > 0) ? part[tid - 1] : 0;
#pragma unroll
    for (int i = 0; i < CH; ++i) {
        if (base + i < NN_) {
            offs[base + i]   = pre + loc[i];
            cursor[base + i] = pre + loc[i];
        }
    }
    if (tid == 1023) offs[NN_] = part[1023];
}

__global__ __launch_bounds__(256) void fill_perm_kernel(
    const int* __restrict__ ei, int* __restrict__ cursor, int* __restrict__ perm)
{
    int e = blockIdx.x * 256 + threadIdx.x;
    if (e < EE_) {
        int p = atomicAdd(&cursor[ei[EE_ + e]], 1);
        perm[p] = e;
    }
}

// ---------------------------------------------------------------------------
// Per-node T build, latency-fixed: batches of EB_ edges; phase 1 loads edge
// meta (perm/ei/attr) with 64 parallel threads; phase 2 gathers feature rows
// with all 256 threads; phase 3 accumulates into LDS T with ds atomics and
// ZERO global loads. One bf16 coalesced writeout at the end.
// ---------------------------------------------------------------------------
template<int C>
__global__ __launch_bounds__(256) void build_T_kernel(
    const int* __restrict__ ei, const float* __restrict__ attr,
    const float* __restrict__ feat, const int* __restrict__ offs,
    const int* __restrict__ perm, unsigned short* __restrict__ Tb)
{
    __shared__ float Tl[KK_ * C];
    __shared__ float s_feat[EB_ * C];
    __shared__ int   s_src[EB_];
    __shared__ int   s_base[EB_];
    __shared__ float s_f0[EB_], s_f1[EB_], s_f2[EB_];

    const int node = blockIdx.x;
    const int tid  = threadIdx.x;
    const int wave = tid >> 6;
    const int lane = tid & 63;
    const int c    = lane & (C - 1);
    const int soff = (C == 32) ? (lane >> 5) : 0;

    for (int i = tid; i < KK_ * C; i += 256) Tl[i] = 0.f;

    const int j0 = offs[node], j1 = offs[node + 1];

    for (int jb = j0; jb < j1; jb += EB_) {
        const int m = min(EB_, j1 - jb);

        // phase 1: edge meta, 64 threads in parallel (2-level chain, all in flight)
        if (tid < m) {
            const int e   = perm[jb + tid];
            const int src = ei[e];
            float f[3]; int i0[3];
#pragma unroll
            for (int d = 0; d < 3; ++d) {
                float u  = attr[e * 3 + d] * 4.0f;
                float fl = floorf(u);
                fl = fminf(fmaxf(fl, 0.0f), 3.0f);
                i0[d] = (int)fl;
                f[d]  = u - fl;
            }
            s_src[tid]  = src;
            s_base[tid] = i0[0] * 25 + i0[1] * 5 + i0[2];
            s_f0[tid] = f[0]; s_f1[tid] = f[1]; s_f2[tid] = f[2];
        }
        __syncthreads();

        // phase 2: gather feature rows, all 256 threads in parallel
        for (int r = tid / C; r < m; r += 256 / C)
            s_feat[r * C + c] = feat[(size_t)s_src[r] * C + c];
        __syncthreads();

        // phase 3: accumulate (LDS only)
        for (int eb = wave; eb < m; eb += 4) {
            const float f0 = s_f0[eb], f1 = s_f1[eb], f2 = s_f2[eb];
            const float g0 = 1.f - f0, g1 = 1.f - f1, g2 = 1.f - f2;
            const int   base = s_base[eb];
            const float xv   = s_feat[eb * C + c];
            if constexpr (C == 64) {
#pragma unroll
                for (int s = 0; s < 8; ++s) {
                    const int off = (s & 1) * 25 + ((s >> 1) & 1) * 5 + (s >> 2);
                    const float basis = ((s & 1) ? f0 : g0) *
                                        ((s & 2) ? f1 : g1) *
                                        ((s & 4) ? f2 : g2);
                    atomicAdd(&Tl[(base + off) * C + c], basis * xv);
                }
            } else {
#pragma unroll
                for (int sp = 0; sp < 8; sp += 2) {
                    const int s = sp + soff;
                    const int off = (s & 1) * 25 + ((s >> 1) & 1) * 5 + (s >> 2);
                    const float basis = ((s & 1) ? f0 : g0) *
                                        ((s & 2) ? f1 : g1) *
                                        ((s & 4) ? f2 : g2);
                    atomicAdd(&Tl[(base + off) * C + c], basis * xv);
                }
            }
        }
        __syncthreads();
    }

    // coalesced bf16 writeout, 2 channels per uint
    unsigned int* To = (unsigned int*)(Tb + (size_t)node * (KK_ * C));
    for (int i = tid; i < (KK_ * C) / 2; i += 256) {
        unsigned int lo = f2bf(Tl[2 * i]);
        unsigned int hi = f2bf(Tl[2 * i + 1]);
        To[i] = lo | (hi << 16);
    }
}

// ---------------------------------------------------------------------------
// Pack weights into transposed bf16 B matrices: Bt[n][k], n = conv*64 + o,
// k = kcell*Cin + c.
// ---------------------------------------------------------------------------
__global__ void pack_x_kernel(const float* __restrict__ Wa,
                              const float* __restrict__ Wb,
                              const float* __restrict__ Wc,
                              unsigned short* __restrict__ B1t)
{
    int gid = blockIdx.x * 256 + threadIdx.x;
    if (gid >= 192 * (KK_ * CIN_)) return;
    int n  = gid / (KK_ * CIN_);
    int kk = gid % (KK_ * CIN_);
    int conv = n >> 6, o = n & 63;
    const float* W = (conv == 0) ? Wa : ((conv == 1) ? Wb : Wc);
    B1t[gid] = f2bf(W[(size_t)kk * 64 + o]);
}

__global__ void pack_h_kernel(const float* __restrict__ Wa,
                              const float* __restrict__ Wb,
                              unsigned short* __restrict__ B2t)
{
    int gid = blockIdx.x * 256 + threadIdx.x;
    if (gid >= 128 * (KK_ * CHID_)) return;
    int n  = gid / (KK_ * CHID_);
    int kk = gid % (KK_ * CHID_);
    int conv = n >> 6, o = n & 63;
    const float* W = (conv == 0) ? Wa : Wb;
    B2t[gid] = f2bf(W[(size_t)kk * 64 + o]);
}

// ---------------------------------------------------------------------------
// MFMA bf16 GEMM with split-K: C[M,NT] += A[M,Kd] x Bt[NT,Kd]^T.
// ---------------------------------------------------------------------------
template<int NT, int STEPS_PER_CHUNK>
__global__ __launch_bounds__(256) void mfma_gemm(
    const unsigned short* __restrict__ A, const unsigned short* __restrict__ Bt,
    float* __restrict__ C, int M, int Kd)
{
    constexpr int NFRAG = NT / 16;
    __shared__ unsigned short As[64][40];
    __shared__ unsigned short Bs[NT][40];

    using bf16x8 = __attribute__((ext_vector_type(8))) short;
    using f32x4  = __attribute__((ext_vector_type(4))) float;

    const int tid  = threadIdx.x;
    const int wave = tid >> 6;
    const int lane = tid & 63;
    const int quad = lane >> 4;
    const int l16  = lane & 15;
    const int m0   = blockIdx.x * 64;

    const int steps_total = Kd >> 5;
    const int s0 = blockIdx.y * STEPS_PER_CHUNK;
    const int s1 = min(steps_total, s0 + STEPS_PER_CHUNK);

    f32x4 acc[NFRAG];
#pragma unroll
    for (int f = 0; f < NFRAG; ++f) acc[f] = (f32x4){0.f, 0.f, 0.f, 0.f};

    const int  arow   = tid >> 2;
    const int  acol   = (tid & 3) * 8;
    const bool avalid = (m0 + arow) < M;
    const unsigned short* Aptr = A + (size_t)(avalid ? (m0 + arow) : 0) * Kd + acol;

    for (int s = s0; s < s1; ++s) {
        const int k0 = s << 5;
        uint4 a4 = make_uint4(0u, 0u, 0u, 0u);
        if (avalid) a4 = *(const uint4*)(Aptr + k0);
        *(uint4*)&As[arow][acol] = a4;

#pragma unroll
        for (int cc = tid; cc < NT * 4; cc += 256) {
            int n = cc >> 2, kc = (cc & 3) * 8;
            *(uint4*)&Bs[n][kc] = *(const uint4*)(Bt + (size_t)n * Kd + k0 + kc);
        }
        __syncthreads();

        bf16x8 af = *(bf16x8*)&As[wave * 16 + l16][quad * 8];
#pragma unroll
        for (int f = 0; f < NFRAG; ++f) {
            bf16x8 bfv = *(bf16x8*)&Bs[f * 16 + l16][quad * 8];
            acc[f] = __builtin_amdgcn_mfma_f32_16x16x32_bf16(af, bfv, acc[f], 0, 0, 0);
        }
        __syncthreads();
    }

#pragma unroll
    for (int f = 0; f < NFRAG; ++f) {
#pragma unroll
        for (int r = 0; r < 4; ++r) {
            int m = m0 + wave * 16 + quad * 4 + r;
            if (m < M) atomicAdd(&C[(size_t)m * NT + f * 16 + l16], acc[f][r]);
        }
    }
}

// ---------------------------------------------------------------------------
// Epilogue: mean-agg + root GEMV + bias + GRU gates, fused.
// ---------------------------------------------------------------------------
__global__ __launch_bounds__(256) void epilogue_kernel(
    const float* __restrict__ C1, const float* __restrict__ C2,
    const int* __restrict__ deg,
    const float* __restrict__ x, const float* __restrict__ hidden,
    const float* __restrict__ root_xr, const float* __restrict__ root_hr,
    const float* __restrict__ root_xz, const float* __restrict__ root_hz,
    const float* __restrict__ root_xn,
    const float* __restrict__ b_xr, const float* __restrict__ b_hr,
    const float* __restrict__ b_xz, const float* __restrict__ b_hz,
    const float* __restrict__ b_xn,
    float* __restrict__ out)
{
    const int node = blockIdx.x * 4 + (threadIdx.x >> 6);
    if (node >= NN_) return;
    const int o = threadIdx.x & 63;

    const float dinv = 1.0f / fmaxf((float)deg[node], 1.0f);
    const float axr = C1[(size_t)node * 192 + o]        * dinv;
    const float axz = C1[(size_t)node * 192 + 64 + o]   * dinv;
    const float axn = C1[(size_t)node * 192 + 128 + o]  * dinv;
    const float ahr = C2[(size_t)node * 128 + o]        * dinv;
    const float ahz = C2[(size_t)node * 128 + 64 + o]   * dinv;

    const float* xr_ = x + (size_t)node * CIN_;
    const float* hr_ = hidden + (size_t)node * CHID_;
    float sxr = 0.f, sxz = 0.f, sxn = 0.f;
#pragma unroll
    for (int c = 0; c < CIN_; ++c) {
        float xv = xr_[c];
        sxr += xv * root_xr[c * 64 + o];
        sxz += xv * root_xz[c * 64 + o];
        sxn += xv * root_xn[c * 64 + o];
    }
    float shr = 0.f, shz = 0.f;
#pragma unroll
    for (int c = 0; c < CHID_; ++c) {
        float hv = hr_[c];
        shr += hv * root_hr[c * 64 + o];
        shz += hv * root_hz[c * 64 + o];
    }

    const float conv_xr = axr + sxr + b_xr[o];
    const float conv_xz = axz + sxz + b_xz[o];
    const float conv_xn = axn + sxn + b_xn[o];
    const float hr_out  = ahr + shr + b_hr[o];
    const float conv_hz = ahz + shz + b_hz[o];

    const float r  = 1.0f / (1.0f + expf(-(conv_xr + hr_out)));
    const float z  = 1.0f / (1.0f + expf(-(conv_xz + conv_hz)));
    const float nn = tanhf(conv_xn + r * hr_out);
    out[(size_t)node * 64 + o] = (1.0f - z) * nn + z * hr_[o];
}

// ---------------------------------------------------------------------------
extern "C" void kernel_launch(void* const* d_in, const int* in_sizes, int n_in,
                              void* d_out, int out_size, void* d_ws, size_t ws_size,
                              hipStream_t stream)
{
    const float* x       = (const float*)d_in[0];
    const float* hidden  = (const float*)d_in[1];
    const int*   ei      = (const int*)  d_in[2];
    const float* attr    = (const float*)d_in[3];
    const float* W_xr    = (const float*)d_in[4];
    const float* root_xr = (const float*)d_in[5];
    const float* b_xr    = (const float*)d_in[6];
    const float* W_hr    = (const float*)d_in[7];
    const float* root_hr = (const float*)d_in[8];
    const float* b_hr    = (const float*)d_in[9];
    const float* W_xz    = (const float*)d_in[10];
    const float* root_xz = (const float*)d_in[11];
    const float* b_xz    = (const float*)d_in[12];
    const float* W_hz    = (const float*)d_in[13];
    const float* root_hz = (const float*)d_in[14];
    const float* b_hz    = (const float*)d_in[15];
    const float* W_xn    = (const float*)d_in[16];
    const float* root_xn = (const float*)d_in[17];
    const float* b_xn    = (const float*)d_in[18];
    // d_in[19..21] (W_hn/root_hn/b_hn) are dead: reference reuses hr_out.
    float* out = (float*)d_out;

    // Workspace layout (~108 MB).
    char* w = (char*)d_ws;
    unsigned short* Tb  = (unsigned short*)w; w += (size_t)NN_ * KK_ * CHID_ * 2;  // 96 MB
    unsigned short* B1t = (unsigned short*)w; w += (size_t)192 * KK_ * CIN_  * 2;
    unsigned short* B2t = (unsigned short*)w; w += (size_t)128 * KK_ * CHID_ * 2;
    float* C1   = (float*)w; w += (size_t)NN_ * 192 * 4;
    float* C2   = (float*)w; w += (size_t)NN_ * 128 * 4;
    int* deg    = (int*)w;   w += (size_t)NN_ * 4;
    int* offs   = (int*)w;   w += (size_t)(NN_ + 4) * 4;
    int* cursor = (int*)w;   w += (size_t)NN_ * 4;
    int* perm   = (int*)w;   w += (size_t)EE_ * 4;

    const int MT = (NN_ + 63) / 64;   // 94 m-tiles

    // ---- bucket edges by dst (shared by both passes) ----
    hipMemsetAsync(deg, 0, (size_t)NN_ * 4, stream);
    hipMemsetAsync(C1, 0, (size_t)NN_ * 192 * 4, stream);
    hipMemsetAsync(C2, 0, (size_t)NN_ * 128 * 4, stream);
    count_deg_kernel<<<(EE_ + 255) / 256, 256, 0, stream>>>(ei, deg);
    scan_kernel<<<1, 1024, 0, stream>>>(deg, offs, cursor);
    fill_perm_kernel<<<(EE_ + 255) / 256, 256, 0, stream>>>(ei, cursor, perm);

    // ---- weight packs (independent of T) ----
    pack_x_kernel<<<(192 * KK_ * CIN_ + 255) / 256, 256, 0, stream>>>(W_xr, W_xz, W_xn, B1t);
    pack_h_kernel<<<(128 * KK_ * CHID_ + 255) / 256, 256, 0, stream>>>(W_hr, W_hz, B2t);

    // ---- x family: T_x (bf16) -> C1 = T_x @ [W_xr | W_xz | W_xn] ----
    build_T_kernel<CIN_><<<NN_, 256, 0, stream>>>(ei, attr, x, offs, perm, Tb);
    mfma_gemm<192, 16><<<dim3(MT, 8), 256, 0, stream>>>(Tb, B1t, C1, NN_, KK_ * CIN_);

    // ---- h family: T_h (bf16) -> C2 = T_h @ [W_hr | W_hz] ----
    build_T_kernel<CHID_><<<NN_, 256, 0, stream>>>(ei, attr, hidden, offs, perm, Tb);
    mfma_gemm<128, 16><<<dim3(MT, 16), 256, 0, stream>>>(Tb, B2t, C2, NN_, KK_ * CHID_);

    // ---- fused GRU epilogue ----
    epilogue_kernel<<<(NN_ + 3) / 4, 256, 0, stream>>>(
        C1, C2, deg, x, hidden,
        root_xr, root_hr, root_xz, root_hz, root_xn,
        b_xr, b_hr, b_xz, b_hz, b_xn, out);
}

// Round 5
// 524.947 us; speedup vs baseline: 2.0876x; 2.0876x over previous
//
#include <hip/hip_runtime.h>
#include <math.h>

#define NN_   6000
#define EE_   192000
#define CIN_  32
#define CHID_ 64
#define KK_   125   // 5^3 spline kernel cells
#define SS_   8     // 2^3 corners

// fp32 -> bf16 round-to-nearest-even
static __device__ __forceinline__ unsigned short f2bf(float f) {
    unsigned int u = __builtin_bit_cast(unsigned int, f);
    u += 0x7fff + ((u >> 16) & 1);
    return (unsigned short)(u >> 16);
}

// ---------------------------------------------------------------------------
// deg count (for mean aggregation in epilogue)
// ---------------------------------------------------------------------------
__global__ __launch_bounds__(256) void count_deg_kernel(
    const int* __restrict__ ei, int* __restrict__ deg)
{
    int e = blockIdx.x * 256 + threadIdx.x;
    if (e < EE_) atomicAdd(&deg[ei[EE_ + e]], 1);
}

// ---------------------------------------------------------------------------
// Edge-parallel scatter with packed-bf16 global atomics:
//   T[dst, idx, 2p..2p+1] += basis * feat[src, 2p..2p+1]   (bf16x2 atomic)
// Thread = (edge, s, channel-pair). 2x fewer atomic lanes than fp32 and T is
// half the bytes -> halves the atomic RMW write-through traffic vs R2.
// ---------------------------------------------------------------------------
template<int C>
__global__ __launch_bounds__(256) void scatter_pk(
    const int* __restrict__ ei, const float* __restrict__ attr,
    const float* __restrict__ feat, unsigned short* __restrict__ Tb)
{
    constexpr int TPE = 8 * (C / 2);        // threads per edge: 256 (C=64), 128 (C=32)
    constexpr int EPB = 256 / TPE;          // edges per block: 1 or 2
    const int tid  = threadIdx.x;
    const int e    = blockIdx.x * EPB + ((EPB == 1) ? 0 : (tid / TPE));
    const int t    = tid % TPE;
    const int s    = t / (C / 2);
    const int pair = t % (C / 2);

    const int src = ei[e];
    const int dst = ei[EE_ + e];

    float f[3]; int i0[3];
#pragma unroll
    for (int d = 0; d < 3; ++d) {
        float u  = attr[e * 3 + d] * 4.0f;
        float fl = floorf(u);
        fl = fminf(fmaxf(fl, 0.0f), 3.0f);   // clip to [0, KS-2]
        i0[d] = (int)fl;
        f[d]  = u - fl;
    }
    const int b0 = s & 1, b1 = (s >> 1) & 1, b2 = (s >> 2) & 1;
    const int idx = (i0[0] + b0) * 25 + (i0[1] + b1) * 5 + (i0[2] + b2);
    const float basis = (b0 ? f[0] : 1.0f - f[0]) *
                        (b1 ? f[1] : 1.0f - f[1]) *
                        (b2 ? f[2] : 1.0f - f[2]);

    const float2 fv = *(const float2*)(feat + (size_t)src * C + 2 * pair);
    const unsigned int data = (unsigned int)f2bf(basis * fv.x) |
                              ((unsigned int)f2bf(basis * fv.y) << 16);
    unsigned short* p = Tb + ((size_t)dst * KK_ + idx) * C + 2 * pair;
    asm volatile("global_atomic_pk_add_bf16 %0, %1, off"
                 :: "v"(p), "v"(data) : "memory");
}

// ---------------------------------------------------------------------------
// Pack weights into transposed bf16 B matrices: Bt[n][k], n = conv*64 + o,
// k = kcell*Cin + c.
// ---------------------------------------------------------------------------
__global__ void pack_x_kernel(const float* __restrict__ Wa,
                              const float* __restrict__ Wb,
                              const float* __restrict__ Wc,
                              unsigned short* __restrict__ B1t)
{
    int gid = blockIdx.x * 256 + threadIdx.x;
    if (gid >= 192 * (KK_ * CIN_)) return;
    int n  = gid / (KK_ * CIN_);
    int kk = gid % (KK_ * CIN_);
    int conv = n >> 6, o = n & 63;
    const float* W = (conv == 0) ? Wa : ((conv == 1) ? Wb : Wc);
    B1t[gid] = f2bf(W[(size_t)kk * 64 + o]);
}

__global__ void pack_h_kernel(const float* __restrict__ Wa,
                              const float* __restrict__ Wb,
                              unsigned short* __restrict__ B2t)
{
    int gid = blockIdx.x * 256 + threadIdx.x;
    if (gid >= 128 * (KK_ * CHID_)) return;
    int n  = gid / (KK_ * CHID_);
    int kk = gid % (KK_ * CHID_);
    int conv = n >> 6, o = n & 63;
    const float* W = (conv == 0) ? Wa : Wb;
    B2t[gid] = f2bf(W[(size_t)kk * 64 + o]);
}

// ---------------------------------------------------------------------------
// MFMA bf16 GEMM with split-K: C[M,NT] += A[M,Kd] x Bt[NT,Kd]^T.
// A and Bt bf16. 64-row tile x full NT, 4 waves, mfma_f32_16x16x32_bf16,
// fp32 atomicAdd into C (C is L2-resident, 3-4.6 MB).
// ---------------------------------------------------------------------------
template<int NT, int STEPS_PER_CHUNK>
__global__ __launch_bounds__(256) void mfma_gemm(
    const unsigned short* __restrict__ A, const unsigned short* __restrict__ Bt,
    float* __restrict__ C, int M, int Kd)
{
    constexpr int NFRAG = NT / 16;
    __shared__ unsigned short As[64][40];
    __shared__ unsigned short Bs[NT][40];

    using bf16x8 = __attribute__((ext_vector_type(8))) short;
    using f32x4  = __attribute__((ext_vector_type(4))) float;

    const int tid  = threadIdx.x;
    const int wave = tid >> 6;
    const int lane = tid & 63;
    const int quad = lane >> 4;
    const int l16  = lane & 15;
    const int m0   = blockIdx.x * 64;

    const int steps_total = Kd >> 5;
    const int s0 = blockIdx.y * STEPS_PER_CHUNK;
    const int s1 = min(steps_total, s0 + STEPS_PER_CHUNK);

    f32x4 acc[NFRAG];
#pragma unroll
    for (int f = 0; f < NFRAG; ++f) acc[f] = (f32x4){0.f, 0.f, 0.f, 0.f};

    const int  arow   = tid >> 2;
    const int  acol   = (tid & 3) * 8;
    const bool avalid = (m0 + arow) < M;
    const unsigned short* Aptr = A + (size_t)(avalid ? (m0 + arow) : 0) * Kd + acol;

    for (int s = s0; s < s1; ++s) {
        const int k0 = s << 5;
        uint4 a4 = make_uint4(0u, 0u, 0u, 0u);
        if (avalid) a4 = *(const uint4*)(Aptr + k0);
        *(uint4*)&As[arow][acol] = a4;

#pragma unroll
        for (int cc = tid; cc < NT * 4; cc += 256) {
            int n = cc >> 2, kc = (cc & 3) * 8;
            *(uint4*)&Bs[n][kc] = *(const uint4*)(Bt + (size_t)n * Kd + k0 + kc);
        }
        __syncthreads();

        bf16x8 af = *(bf16x8*)&As[wave * 16 + l16][quad * 8];
#pragma unroll
        for (int f = 0; f < NFRAG; ++f) {
            bf16x8 bfv = *(bf16x8*)&Bs[f * 16 + l16][quad * 8];
            acc[f] = __builtin_amdgcn_mfma_f32_16x16x32_bf16(af, bfv, acc[f], 0, 0, 0);
        }
        __syncthreads();
    }

#pragma unroll
    for (int f = 0; f < NFRAG; ++f) {
#pragma unroll
        for (int r = 0; r < 4; ++r) {
            int m = m0 + wave * 16 + quad * 4 + r;
            if (m < M) atomicAdd(&C[(size_t)m * NT + f * 16 + l16], acc[f][r]);
        }
    }
}

// ---------------------------------------------------------------------------
// Epilogue: mean-agg + root GEMV + bias + GRU gates, fused.
// ---------------------------------------------------------------------------
__global__ __launch_bounds__(256) void epilogue_kernel(
    const float* __restrict__ C1, const float* __restrict__ C2,
    const int* __restrict__ deg,
    const float* __restrict__ x, const float* __restrict__ hidden,
    const float* __restrict__ root_xr, const float* __restrict__ root_hr,
    const float* __restrict__ root_xz, const float* __restrict__ root_hz,
    const float* __restrict__ root_xn,
    const float* __restrict__ b_xr, const float* __restrict__ b_hr,
    const float* __restrict__ b_xz, const float* __restrict__ b_hz,
    const float* __restrict__ b_xn,
    float* __restrict__ out)
{
    const int node = blockIdx.x * 4 + (threadIdx.x >> 6);
    if (node >= NN_) return;
    const int o = threadIdx.x & 63;

    const float dinv = 1.0f / fmaxf((float)deg[node], 1.0f);
    const float axr = C1[(size_t)node * 192 + o]        * dinv;
    const float axz = C1[(size_t)node * 192 + 64 + o]   * dinv;
    const float axn = C1[(size_t)node * 192 + 128 + o]  * dinv;
    const float ahr = C2[(size_t)node * 128 + o]        * dinv;
    const float ahz = C2[(size_t)node * 128 + 64 + o]   * dinv;

    const float* xr_ = x + (size_t)node * CIN_;
    const float* hr_ = hidden + (size_t)node * CHID_;
    float sxr = 0.f, sxz = 0.f, sxn = 0.f;
#pragma unroll
    for (int c = 0; c < CIN_; ++c) {
        float xv = xr_[c];
        sxr += xv * root_xr[c * 64 + o];
        sxz += xv * root_xz[c * 64 + o];
        sxn += xv * root_xn[c * 64 + o];
    }
    float shr = 0.f, shz = 0.f;
#pragma unroll
    for (int c = 0; c < CHID_; ++c) {
        float hv = hr_[c];
        shr += hv * root_hr[c * 64 + o];
        shz += hv * root_hz[c * 64 + o];
    }

    const float conv_xr = axr + sxr + b_xr[o];
    const float conv_xz = axz + sxz + b_xz[o];
    const float conv_xn = axn + sxn + b_xn[o];
    const float hr_out  = ahr + shr + b_hr[o];
    const float conv_hz = ahz + shz + b_hz[o];

    const float r  = 1.0f / (1.0f + expf(-(conv_xr + hr_out)));
    const float z  = 1.0f / (1.0f + expf(-(conv_xz + conv_hz)));
    const float nn = tanhf(conv_xn + r * hr_out);
    out[(size_t)node * 64 + o] = (1.0f - z) * nn + z * hr_[o];
}

// ---------------------------------------------------------------------------
extern "C" void kernel_launch(void* const* d_in, const int* in_sizes, int n_in,
                              void* d_out, int out_size, void* d_ws, size_t ws_size,
                              hipStream_t stream)
{
    const float* x       = (const float*)d_in[0];
    const float* hidden  = (const float*)d_in[1];
    const int*   ei      = (const int*)  d_in[2];
    const float* attr    = (const float*)d_in[3];
    const float* W_xr    = (const float*)d_in[4];
    const float* root_xr = (const float*)d_in[5];
    const float* b_xr    = (const float*)d_in[6];
    const float* W_hr    = (const float*)d_in[7];
    const float* root_hr = (const float*)d_in[8];
    const float* b_hr    = (const float*)d_in[9];
    const float* W_xz    = (const float*)d_in[10];
    const float* root_xz = (const float*)d_in[11];
    const float* b_xz    = (const float*)d_in[12];
    const float* W_hz    = (const float*)d_in[13];
    const float* root_hz = (const float*)d_in[14];
    const float* b_hz    = (const float*)d_in[15];
    const float* W_xn    = (const float*)d_in[16];
    const float* root_xn = (const float*)d_in[17];
    const float* b_xn    = (const float*)d_in[18];
    // d_in[19..21] (W_hn/root_hn/b_hn) are dead: reference reuses hr_out.
    float* out = (float*)d_out;

    // Workspace layout (~155 MB): separate bf16 T for x and h passes.
    char* w = (char*)d_ws;
    unsigned short* Tx  = (unsigned short*)w; w += (size_t)NN_ * KK_ * CIN_  * 2;  // 48 MB
    unsigned short* Th  = (unsigned short*)w; w += (size_t)NN_ * KK_ * CHID_ * 2;  // 96 MB
    unsigned short* B1t = (unsigned short*)w; w += (size_t)192 * KK_ * CIN_  * 2;
    unsigned short* B2t = (unsigned short*)w; w += (size_t)128 * KK_ * CHID_ * 2;
    float* C1   = (float*)w; w += (size_t)NN_ * 192 * 4;
    float* C2   = (float*)w; w += (size_t)NN_ * 128 * 4;
    int* deg    = (int*)w;   w += (size_t)NN_ * 4;

    const int MT = (NN_ + 63) / 64;   // 94 m-tiles

    // ---- zero T / C / deg ----
    hipMemsetAsync(Tx, 0, (size_t)NN_ * KK_ * CIN_  * 2, stream);
    hipMemsetAsync(Th, 0, (size_t)NN_ * KK_ * CHID_ * 2, stream);
    hipMemsetAsync(C1, 0, (size_t)NN_ * 192 * 4, stream);
    hipMemsetAsync(C2, 0, (size_t)NN_ * 128 * 4, stream);
    hipMemsetAsync(deg, 0, (size_t)NN_ * 4, stream);

    count_deg_kernel<<<(EE_ + 255) / 256, 256, 0, stream>>>(ei, deg);

    // ---- weight packs ----
    pack_x_kernel<<<(192 * KK_ * CIN_ + 255) / 256, 256, 0, stream>>>(W_xr, W_xz, W_xn, B1t);
    pack_h_kernel<<<(128 * KK_ * CHID_ + 255) / 256, 256, 0, stream>>>(W_hr, W_hz, B2t);

    // ---- edge-parallel pk-bf16 scatters ----
    scatter_pk<CIN_><<<EE_ / 2, 256, 0, stream>>>(ei, attr, x, Tx);       // 2 edges/block
    scatter_pk<CHID_><<<EE_, 256, 0, stream>>>(ei, attr, hidden, Th);     // 1 edge/block

    // ---- GEMMs ----
    mfma_gemm<192, 16><<<dim3(MT, 8), 256, 0, stream>>>(Tx, B1t, C1, NN_, KK_ * CIN_);
    mfma_gemm<128, 16><<<dim3(MT, 16), 256, 0, stream>>>(Th, B2t, C2, NN_, KK_ * CHID_);

    // ---- fused GRU epilogue ----
    epilogue_kernel<<<(NN_ + 3) / 4, 256, 0, stream>>>(
        C1, C2, deg, x, hidden,
        root_xr, root_hr, root_xz, root_hz, root_xn,
        b_xr, b_hr, b_xz, b_hz, b_xn, out);
}

// Round 6
// 496.717 us; speedup vs baseline: 2.2062x; 1.0568x over previous
//
#include <hip/hip_runtime.h>
#include <math.h>

#define NN_   6000
#define EE_   192000
#define CIN_  32
#define CHID_ 64
#define KK_   125   // 5^3 spline kernel cells
#define EB_   64    // edge batch per block in build_T

// fp32 -> bf16 round-to-nearest-even
static __device__ __forceinline__ unsigned short f2bf(float f) {
    unsigned int u = __builtin_bit_cast(unsigned int, f);
    u += 0x7fff + ((u >> 16) & 1);
    return (unsigned short)(u >> 16);
}
static __device__ __forceinline__ float bf2f(unsigned short h) {
    unsigned int u = ((unsigned int)h) << 16;
    return __builtin_bit_cast(float, u);
}

// ---------------------------------------------------------------------------
// Bucketing: counting sort of edges by dst.
// ---------------------------------------------------------------------------
__global__ __launch_bounds__(256) void count_deg_kernel(
    const int* __restrict__ ei, int* __restrict__ deg)
{
    int e = blockIdx.x * 256 + threadIdx.x;
    if (e < EE_) atomicAdd(&deg[ei[EE_ + e]], 1);
}

__global__ __launch_bounds__(1024) void scan_kernel(
    const int* __restrict__ deg, int* __restrict__ offs, int* __restrict__ cursor)
{
    __shared__ int part[1024];
    const int tid = threadIdx.x;
    const int CH = (NN_ + 1023) / 1024;   // 6
    const int base = tid * CH;
    int loc[CH];
    int s = 0;
#pragma unroll
    for (int i = 0; i < CH; ++i) {
        int v = (base + i < NN_) ? deg[base + i] : 0;
        loc[i] = s; s += v;
    }
    part[tid] = s;
    __syncthreads();
    for (int off = 1; off < 1024; off <<= 1) {
        int v = (tid >= off) ? part[tid - off] : 0;
        __syncthreads();
        part[tid] += v;
        __syncthreads();
    }
    const int pre = (tid > 0) ? part[tid - 1] : 0;
#pragma unroll
    for (int i = 0; i < CH; ++i) {
        if (base + i < NN_) {
            offs[base + i]   = pre + loc[i];
            cursor[base + i] = pre + loc[i];
        }
    }
    if (tid == 1023) offs[NN_] = part[1023];
}

__global__ __launch_bounds__(256) void fill_perm_kernel(
    const int* __restrict__ ei, int* __restrict__ cursor, int* __restrict__ perm)
{
    int e = blockIdx.x * 256 + threadIdx.x;
    if (e < EE_) {
        int p = atomicAdd(&cursor[ei[EE_ + e]], 1);
        perm[p] = e;
    }
}

// ---------------------------------------------------------------------------
// Per-node T build, NON-ATOMIC: block = dst node. Waves own disjoint
// channel-pairs (pidx = wave*PPW + pl), so each LDS T-cell has exactly one
// owner -> plain b64 read/add/write, no ds atomics (measured ~220cyc/op in
// R3/R4 vs ~6-12 for plain RMW). Lane = (corner s, pair pl). Batched edge
// meta + feature prefetch as in R4. Full rows written -> no global memset.
// ---------------------------------------------------------------------------
template<int C>
__global__ __launch_bounds__(256) void build_T_kernel(
    const int* __restrict__ ei, const float* __restrict__ attr,
    const float* __restrict__ feat, const int* __restrict__ offs,
    const int* __restrict__ perm, unsigned short* __restrict__ Tb)
{
    constexpr int PAD   = C + 2;       // pad keeps b64 align, spreads banks
    constexpr int NPAIR = C / 2;       // 32 (C=64) / 16 (C=32)
    constexpr int PPW   = NPAIR / 4;   // pairs owned per wave: 8 / 4
    __shared__ float  Tl[KK_ * PAD];
    __shared__ float4 s_meta[EB_];     // f0,f1,f2, base(int bits)
    __shared__ int    s_src[EB_];
    __shared__ float  s_feat[EB_ * C];

    const int node = blockIdx.x;
    const int tid  = threadIdx.x;
    const int wave = tid >> 6;
    const int lane = tid & 63;

    for (int i = tid; i < KK_ * PAD; i += 256) Tl[i] = 0.f;

    const int j0 = offs[node], j1 = offs[node + 1];

    // phase-3 lane mapping (corner, owned pair)
    const int  s_c  = lane / PPW;            // 0..7 when active
    const int  pl   = lane % PPW;
    const int  pidx = wave * PPW + pl;       // owned channel pair
    const bool act  = lane < 8 * PPW;        // all 64 (C=64) / lower 32 (C=32)
    const int  cb0 = s_c & 1, cb1 = (s_c >> 1) & 1, cb2 = (s_c >> 2) & 1;
    const int  offc = cb0 * 25 + cb1 * 5 + cb2;

    __syncthreads();

    for (int jb = j0; jb < j1; jb += EB_) {
        const int m = min(EB_, j1 - jb);

        // phase 1: edge meta, 64 parallel threads
        if (tid < m) {
            const int e   = perm[jb + tid];
            const int src = ei[e];
            float f[3]; int i0[3];
#pragma unroll
            for (int d = 0; d < 3; ++d) {
                float u  = attr[e * 3 + d] * 4.0f;
                float fl = floorf(u);
                fl = fminf(fmaxf(fl, 0.0f), 3.0f);
                i0[d] = (int)fl;
                f[d]  = u - fl;
            }
            s_meta[tid] = make_float4(f[0], f[1], f[2],
                __int_as_float(i0[0] * 25 + i0[1] * 5 + i0[2]));
            s_src[tid] = src;
        }
        __syncthreads();

        // phase 2: gather feature rows, all threads
        constexpr int F4R = C / 4;
        for (int u = tid; u < m * F4R; u += 256) {
            int r = u / F4R, q = u % F4R;
            *(float4*)&s_feat[r * C + q * 4] =
                *(const float4*)&feat[(size_t)s_src[r] * C + q * 4];
        }
        __syncthreads();

        // phase 3: race-free LDS accumulate (zero global traffic, no atomics)
        if (act) {
            for (int eb = 0; eb < m; ++eb) {
                const float4 mt = s_meta[eb];
                const int base  = __float_as_int(mt.w);
                const float p = (cb0 ? mt.x : 1.f - mt.x) *
                                (cb1 ? mt.y : 1.f - mt.y) *
                                (cb2 ? mt.z : 1.f - mt.z);
                const float2 fv = *(const float2*)&s_feat[eb * C + 2 * pidx];
                float* cell = &Tl[(base + offc) * PAD + 2 * pidx];
                cell[0] += p * fv.x;
                cell[1] += p * fv.y;
            }
        }
        __syncthreads();
    }

    // writeout bf16, coalesced
    unsigned int* To = (unsigned int*)(Tb + (size_t)node * (KK_ * C));
    for (int u = tid; u < KK_ * NPAIR; u += 256) {
        int k = u / NPAIR, pp = u % NPAIR;
        unsigned int lo = f2bf(Tl[k * PAD + 2 * pp]);
        unsigned int hi = f2bf(Tl[k * PAD + 2 * pp + 1]);
        To[u] = lo | (hi << 16);
    }
}

// ---------------------------------------------------------------------------
// Pack weights into transposed bf16 B matrices: Bt[n][k], n = conv*64 + o.
// ---------------------------------------------------------------------------
__global__ void pack_x_kernel(const float* __restrict__ Wa,
                              const float* __restrict__ Wb,
                              const float* __restrict__ Wc,
                              unsigned short* __restrict__ B1t)
{
    int gid = blockIdx.x * 256 + threadIdx.x;
    if (gid >= 192 * (KK_ * CIN_)) return;
    int n  = gid / (KK_ * CIN_);
    int kk = gid % (KK_ * CIN_);
    int conv = n >> 6, o = n & 63;
    const float* W = (conv == 0) ? Wa : ((conv == 1) ? Wb : Wc);
    B1t[gid] = f2bf(W[(size_t)kk * 64 + o]);
}

__global__ void pack_h_kernel(const float* __restrict__ Wa,
                              const float* __restrict__ Wb,
                              unsigned short* __restrict__ B2t)
{
    int gid = blockIdx.x * 256 + threadIdx.x;
    if (gid >= 128 * (KK_ * CHID_)) return;
    int n  = gid / (KK_ * CHID_);
    int kk = gid % (KK_ * CHID_);
    int conv = n >> 6, o = n & 63;
    const float* W = (conv == 0) ? Wa : Wb;
    B2t[gid] = f2bf(W[(size_t)kk * 64 + o]);
}

// ---------------------------------------------------------------------------
// MFMA bf16 GEMM, split-K, VGPR-prefetch double-buffered staging.
// Output is TRANSPOSED bf16: Ct[n][m], flushed with global_atomic_pk_add_bf16
// (per-lane acc rows are m-consecutive -> pk-packable; precision OK since
// epilogue divides by deg). Half the flush wave-ops, quarter the bytes vs
// fp32 atomics.
// ---------------------------------------------------------------------------
template<int NT, int SPC>
__global__ __launch_bounds__(256) void mfma_gemm(
    const unsigned short* __restrict__ A, const unsigned short* __restrict__ Bt,
    unsigned short* __restrict__ Ct, int M, int Kd)
{
    constexpr int NFRAG = NT / 16;
    constexpr int BLD   = NT / 64;     // uint4 B-loads per thread per step
    __shared__ unsigned short As[64][40];
    __shared__ unsigned short Bs[NT][40];

    using bf16x8 = __attribute__((ext_vector_type(8))) short;
    using f32x4  = __attribute__((ext_vector_type(4))) float;

    const int tid  = threadIdx.x;
    const int wave = tid >> 6;
    const int lane = tid & 63;
    const int quad = lane >> 4;
    const int l16  = lane & 15;
    const int m0   = blockIdx.x * 64;

    const int steps = Kd >> 5;
    const int s0 = blockIdx.y * SPC;
    const int s1 = min(steps, s0 + SPC);

    f32x4 acc[NFRAG];
#pragma unroll
    for (int f = 0; f < NFRAG; ++f) acc[f] = (f32x4){0.f, 0.f, 0.f, 0.f};

    const int  arow   = tid >> 2;
    const int  acol   = (tid & 3) * 8;
    const bool avalid = (m0 + arow) < M;
    const unsigned short* Aptr = A + (size_t)(avalid ? (m0 + arow) : 0) * Kd + acol;

    uint4 a_st = make_uint4(0u, 0u, 0u, 0u);
    uint4 b_st[BLD];
    if (avalid) a_st = *(const uint4*)(Aptr + (s0 << 5));
#pragma unroll
    for (int j = 0; j < BLD; ++j) {
        int u = tid + 256 * j;
        b_st[j] = *(const uint4*)(Bt + (size_t)(u >> 2) * Kd + (s0 << 5) + (u & 3) * 8);
    }

    for (int s = s0; s < s1; ++s) {
        __syncthreads();
        *(uint4*)&As[arow][acol] = a_st;
#pragma unroll
        for (int j = 0; j < BLD; ++j) {
            int u = tid + 256 * j;
            *(uint4*)&Bs[u >> 2][(u & 3) * 8] = b_st[j];
        }
        __syncthreads();
        if (s + 1 < s1) {                    // prefetch next tile (overlaps MFMA)
            if (avalid) a_st = *(const uint4*)(Aptr + ((s + 1) << 5));
#pragma unroll
            for (int j = 0; j < BLD; ++j) {
                int u = tid + 256 * j;
                b_st[j] = *(const uint4*)(Bt + (size_t)(u >> 2) * Kd + ((s + 1) << 5) + (u & 3) * 8);
            }
        }
        bf16x8 af = *(bf16x8*)&As[wave * 16 + l16][quad * 8];
#pragma unroll
        for (int f = 0; f < NFRAG; ++f) {
            bf16x8 bfv = *(bf16x8*)&Bs[f * 16 + l16][quad * 8];
            acc[f] = __builtin_amdgcn_mfma_f32_16x16x32_bf16(af, bfv, acc[f], 0, 0, 0);
        }
    }

    // flush: transposed pk-bf16 atomics (rows m-consecutive per lane)
    const int mb = m0 + wave * 16 + quad * 4;
    if (mb < M) {
#pragma unroll
        for (int f = 0; f < NFRAG; ++f) {
            const int n = f * 16 + l16;
            unsigned short* p0 = Ct + (size_t)n * M + mb;
            unsigned int d0 = (unsigned int)f2bf(acc[f][0]) | ((unsigned int)f2bf(acc[f][1]) << 16);
            unsigned int d1 = (unsigned int)f2bf(acc[f][2]) | ((unsigned int)f2bf(acc[f][3]) << 16);
            asm volatile("global_atomic_pk_add_bf16 %0, %1, off" :: "v"(p0), "v"(d0) : "memory");
            asm volatile("global_atomic_pk_add_bf16 %0, %1, off" :: "v"(p0 + 2), "v"(d1) : "memory");
        }
    }
}

// ---------------------------------------------------------------------------
// Epilogue for transposed C: block = 64 nodes. x/h tiles staged in LDS
// (padded, scalar access, 2-way max). C-slices read coalesced (lane = node).
// ---------------------------------------------------------------------------
__global__ __launch_bounds__(256) void epilogue_kernel(
    const unsigned short* __restrict__ C1t, const unsigned short* __restrict__ C2t,
    const int* __restrict__ deg,
    const float* __restrict__ x, const float* __restrict__ hidden,
    const float* __restrict__ root_xr, const float* __restrict__ root_hr,
    const float* __restrict__ root_xz, const float* __restrict__ root_hz,
    const float* __restrict__ root_xn,
    const float* __restrict__ b_xr, const float* __restrict__ b_hr,
    const float* __restrict__ b_xz, const float* __restrict__ b_hz,
    const float* __restrict__ b_xn,
    float* __restrict__ out)
{
    __shared__ float xs[64][33];
    __shared__ float hs[64][65];
    __shared__ float os[64][65];
    const int tid = threadIdx.x;
    const int m0  = blockIdx.x * 64;
    const int R   = min(64, NN_ - m0);

    for (int u = tid; u < 64 * 8; u += 256) {        // x: 64 rows x 32
        int r = u >> 3, q = u & 7;
        if (r < R) {
            float4 v = *(const float4*)&x[(size_t)(m0 + r) * 32 + q * 4];
            xs[r][q * 4] = v.x; xs[r][q * 4 + 1] = v.y;
            xs[r][q * 4 + 2] = v.z; xs[r][q * 4 + 3] = v.w;
        }
    }
    for (int u = tid; u < 64 * 16; u += 256) {       // hidden: 64 rows x 64
        int r = u >> 4, q = u & 15;
        if (r < R) {
            float4 v = *(const float4*)&hidden[(size_t)(m0 + r) * 64 + q * 4];
            hs[r][q * 4] = v.x; hs[r][q * 4 + 1] = v.y;
            hs[r][q * 4 + 2] = v.z; hs[r][q * 4 + 3] = v.w;
        }
    }
    __syncthreads();

    const int nl = tid & 63, og = tid >> 6;
    const int m  = m0 + nl;
    if (nl < R) {
        const float dinv = 1.0f / fmaxf((float)deg[m], 1.0f);
#pragma unroll 1
        for (int k = 0; k < 16; ++k) {
            const int o = og * 16 + k;
            const float axr = bf2f(C1t[(size_t)o * NN_ + m])          * dinv;
            const float axz = bf2f(C1t[(size_t)(64 + o) * NN_ + m])   * dinv;
            const float axn = bf2f(C1t[(size_t)(128 + o) * NN_ + m])  * dinv;
            const float ahr = bf2f(C2t[(size_t)o * NN_ + m])          * dinv;
            const float ahz = bf2f(C2t[(size_t)(64 + o) * NN_ + m])   * dinv;

            float sxr = 0.f, sxz = 0.f, sxn = 0.f;
#pragma unroll
            for (int c = 0; c < CIN_; ++c) {
                float xv = xs[nl][c];
                sxr += xv * root_xr[c * 64 + o];
                sxz += xv * root_xz[c * 64 + o];
                sxn += xv * root_xn[c * 64 + o];
            }
            float shr = 0.f, shz = 0.f;
#pragma unroll
            for (int c = 0; c < CHID_; ++c) {
                float hv = hs[nl][c];
                shr += hv * root_hr[c * 64 + o];
                shz += hv * root_hz[c * 64 + o];
            }

            const float conv_xr = axr + sxr + b_xr[o];
            const float conv_xz = axz + sxz + b_xz[o];
            const float conv_xn = axn + sxn + b_xn[o];
            const float hr_out  = ahr + shr + b_hr[o];
            const float conv_hz = ahz + shz + b_hz[o];

            const float rg = 1.0f / (1.0f + expf(-(conv_xr + hr_out)));
            const float zg = 1.0f / (1.0f + expf(-(conv_xz + conv_hz)));
            const float ng = tanhf(conv_xn + rg * hr_out);
            os[nl][o] = (1.0f - zg) * ng + zg * hs[nl][o];
        }
    }
    __syncthreads();

    for (int u = tid; u < 64 * 16; u += 256) {
        int r = u >> 4, q = u & 15;
        if (r < R) {
            float4 v = make_float4(os[r][q * 4], os[r][q * 4 + 1],
                                   os[r][q * 4 + 2], os[r][q * 4 + 3]);
            *(float4*)&out[(size_t)(m0 + r) * 64 + q * 4] = v;
        }
    }
}

// ---------------------------------------------------------------------------
extern "C" void kernel_launch(void* const* d_in, const int* in_sizes, int n_in,
                              void* d_out, int out_size, void* d_ws, size_t ws_size,
                              hipStream_t stream)
{
    const float* x       = (const float*)d_in[0];
    const float* hidden  = (const float*)d_in[1];
    const int*   ei      = (const int*)  d_in[2];
    const float* attr    = (const float*)d_in[3];
    const float* W_xr    = (const float*)d_in[4];
    const float* root_xr = (const float*)d_in[5];
    const float* b_xr    = (const float*)d_in[6];
    const float* W_hr    = (const float*)d_in[7];
    const float* root_hr = (const float*)d_in[8];
    const float* b_hr    = (const float*)d_in[9];
    const float* W_xz    = (const float*)d_in[10];
    const float* root_xz = (const float*)d_in[11];
    const float* b_xz    = (const float*)d_in[12];
    const float* W_hz    = (const float*)d_in[13];
    const float* root_hz = (const float*)d_in[14];
    const float* b_hz    = (const float*)d_in[15];
    const float* W_xn    = (const float*)d_in[16];
    const float* root_xn = (const float*)d_in[17];
    const float* b_xn    = (const float*)d_in[18];
    // d_in[19..21] (W_hn/root_hn/b_hn) are dead: reference reuses hr_out.
    float* out = (float*)d_out;

    // Workspace (~152 MB). C1t/C2t adjacent -> one memset.
    char* w = (char*)d_ws;
    unsigned short* Tx  = (unsigned short*)w; w += (size_t)NN_ * KK_ * CIN_  * 2;  // 48 MB
    unsigned short* Th  = (unsigned short*)w; w += (size_t)NN_ * KK_ * CHID_ * 2;  // 96 MB
    unsigned short* B1t = (unsigned short*)w; w += (size_t)192 * KK_ * CIN_  * 2;
    unsigned short* B2t = (unsigned short*)w; w += (size_t)128 * KK_ * CHID_ * 2;
    unsigned short* C1t = (unsigned short*)w; w += (size_t)192 * NN_ * 2;
    unsigned short* C2t = (unsigned short*)w; w += (size_t)128 * NN_ * 2;
    int* deg    = (int*)w;   w += (size_t)NN_ * 4;
    int* offs   = (int*)w;   w += (size_t)(NN_ + 4) * 4;
    int* cursor = (int*)w;   w += (size_t)NN_ * 4;
    int* perm   = (int*)w;   w += (size_t)EE_ * 4;

    const int MT = (NN_ + 63) / 64;   // 94 m-tiles

    hipMemsetAsync(deg, 0, (size_t)NN_ * 4, stream);
    hipMemsetAsync(C1t, 0, (size_t)(192 + 128) * NN_ * 2, stream);

    // ---- bucket edges by dst ----
    count_deg_kernel<<<(EE_ + 255) / 256, 256, 0, stream>>>(ei, deg);
    scan_kernel<<<1, 1024, 0, stream>>>(deg, offs, cursor);
    fill_perm_kernel<<<(EE_ + 255) / 256, 256, 0, stream>>>(ei, cursor, perm);

    // ---- weight packs ----
    pack_x_kernel<<<(192 * KK_ * CIN_ + 255) / 256, 256, 0, stream>>>(W_xr, W_xz, W_xn, B1t);
    pack_h_kernel<<<(128 * KK_ * CHID_ + 255) / 256, 256, 0, stream>>>(W_hr, W_hz, B2t);

    // ---- non-atomic LDS T builds (write full rows; no T memset) ----
    build_T_kernel<CIN_><<<NN_, 256, 0, stream>>>(ei, attr, x, offs, perm, Tx);
    build_T_kernel<CHID_><<<NN_, 256, 0, stream>>>(ei, attr, hidden, offs, perm, Th);

    // ---- GEMMs (transposed pk-bf16 C) ----
    mfma_gemm<192, 16><<<dim3(MT, 8), 256, 0, stream>>>(Tx, B1t, C1t, NN_, KK_ * CIN_);
    mfma_gemm<128, 16><<<dim3(MT, 16), 256, 0, stream>>>(Th, B2t, C2t, NN_, KK_ * CHID_);

    // ---- fused GRU epilogue ----
    epilogue_kernel<<<MT, 256, 0, stream>>>(
        C1t, C2t, deg, x, hidden,
        root_xr, root_hr, root_xz, root_hz, root_xn,
        b_xr, b_hr, b_xz, b_hz, b_xn, out);
}

// Round 7
// 411.364 us; speedup vs baseline: 2.6640x; 1.2075x over previous
//
#include <hip/hip_runtime.h>
#include <math.h>

#define NN_   6000
#define EE_   192000
#define CIN_  32
#define CHID_ 64
#define KK_   125   // 5^3 spline kernel cells
#define EB_   64    // edge batch per block in build_T
#define CH1_  8     // split-K chunks, x-GEMM (steps=125, SPC=16)
#define CH2_  6     // split-K chunks, h-GEMM (steps=250, SPC=42)

// fp32 -> bf16 round-to-nearest-even
static __device__ __forceinline__ unsigned short f2bf(float f) {
    unsigned int u = __builtin_bit_cast(unsigned int, f);
    u += 0x7fff + ((u >> 16) & 1);
    return (unsigned short)(u >> 16);
}

// ---------------------------------------------------------------------------
// Bucketing: counting sort of edges by dst.
// ---------------------------------------------------------------------------
__global__ __launch_bounds__(256) void count_deg_kernel(
    const int* __restrict__ ei, int* __restrict__ deg)
{
    int e = blockIdx.x * 256 + threadIdx.x;
    if (e < EE_) atomicAdd(&deg[ei[EE_ + e]], 1);
}

__global__ __launch_bounds__(1024) void scan_kernel(
    const int* __restrict__ deg, int* __restrict__ offs, int* __restrict__ cursor)
{
    __shared__ int part[1024];
    const int tid = threadIdx.x;
    const int CH = (NN_ + 1023) / 1024;   // 6
    const int base = tid * CH;
    int loc[CH];
    int s = 0;
#pragma unroll
    for (int i = 0; i < CH; ++i) {
        int v = (base + i < NN_) ? deg[base + i] : 0;
        loc[i] = s; s += v;
    }
    part[tid] = s;
    __syncthreads();
    for (int off = 1; off < 1024; off <<= 1) {
        int v = (tid >= off) ? part[tid - off] : 0;
        __syncthreads();
        part[tid] += v;
        __syncthreads();
    }
    const int pre = (tid > 0) ? part[tid - 1] : 0;
#pragma unroll
    for (int i = 0; i < CH; ++i) {
        if (base + i < NN_) {
            offs[base + i]   = pre + loc[i];
            cursor[base + i] = pre + loc[i];
        }
    }
    if (tid == 1023) offs[NN_] = part[1023];
}

__global__ __launch_bounds__(256) void fill_perm_kernel(
    const int* __restrict__ ei, int* __restrict__ cursor, int* __restrict__ perm)
{
    int e = blockIdx.x * 256 + threadIdx.x;
    if (e < EE_) {
        int p = atomicAdd(&cursor[ei[EE_ + e]], 1);
        perm[p] = e;
    }
}

// ---------------------------------------------------------------------------
// Per-node T build, non-atomic (waves own disjoint channel-pairs -> plain
// b64 LDS RMW). Batched edge-meta + feature prefetch. Full rows written ->
// no global memset of T.
// ---------------------------------------------------------------------------
template<int C>
__global__ __launch_bounds__(256) void build_T_kernel(
    const int* __restrict__ ei, const float* __restrict__ attr,
    const float* __restrict__ feat, const int* __restrict__ offs,
    const int* __restrict__ perm, unsigned short* __restrict__ Tb)
{
    constexpr int PAD   = C + 2;
    constexpr int NPAIR = C / 2;
    constexpr int PPW   = NPAIR / 4;
    __shared__ float  Tl[KK_ * PAD];
    __shared__ float4 s_meta[EB_];
    __shared__ int    s_src[EB_];
    __shared__ float  s_feat[EB_ * C];

    const int node = blockIdx.x;
    const int tid  = threadIdx.x;
    const int wave = tid >> 6;
    const int lane = tid & 63;

    for (int i = tid; i < KK_ * PAD; i += 256) Tl[i] = 0.f;

    const int j0 = offs[node], j1 = offs[node + 1];

    const int  s_c  = lane / PPW;
    const int  pl   = lane % PPW;
    const int  pidx = wave * PPW + pl;
    const bool act  = lane < 8 * PPW;
    const int  cb0 = s_c & 1, cb1 = (s_c >> 1) & 1, cb2 = (s_c >> 2) & 1;
    const int  offc = cb0 * 25 + cb1 * 5 + cb2;

    __syncthreads();

    for (int jb = j0; jb < j1; jb += EB_) {
        const int m = min(EB_, j1 - jb);

        if (tid < m) {
            const int e   = perm[jb + tid];
            const int src = ei[e];
            float f[3]; int i0[3];
#pragma unroll
            for (int d = 0; d < 3; ++d) {
                float u  = attr[e * 3 + d] * 4.0f;
                float fl = floorf(u);
                fl = fminf(fmaxf(fl, 0.0f), 3.0f);
                i0[d] = (int)fl;
                f[d]  = u - fl;
            }
            s_meta[tid] = make_float4(f[0], f[1], f[2],
                __int_as_float(i0[0] * 25 + i0[1] * 5 + i0[2]));
            s_src[tid] = src;
        }
        __syncthreads();

        constexpr int F4R = C / 4;
        for (int u = tid; u < m * F4R; u += 256) {
            int r = u / F4R, q = u % F4R;
            *(float4*)&s_feat[r * C + q * 4] =
                *(const float4*)&feat[(size_t)s_src[r] * C + q * 4];
        }
        __syncthreads();

        if (act) {
            for (int eb = 0; eb < m; ++eb) {
                const float4 mt = s_meta[eb];
                const int base  = __float_as_int(mt.w);
                const float p = (cb0 ? mt.x : 1.f - mt.x) *
                                (cb1 ? mt.y : 1.f - mt.y) *
                                (cb2 ? mt.z : 1.f - mt.z);
                const float2 fv = *(const float2*)&s_feat[eb * C + 2 * pidx];
                float* cell = &Tl[(base + offc) * PAD + 2 * pidx];
                cell[0] += p * fv.x;
                cell[1] += p * fv.y;
            }
        }
        __syncthreads();
    }

    unsigned int* To = (unsigned int*)(Tb + (size_t)node * (KK_ * C));
    for (int u = tid; u < KK_ * NPAIR; u += 256) {
        int k = u / NPAIR, pp = u % NPAIR;
        unsigned int lo = f2bf(Tl[k * PAD + 2 * pp]);
        unsigned int hi = f2bf(Tl[k * PAD + 2 * pp + 1]);
        To[u] = lo | (hi << 16);
    }
}

// ---------------------------------------------------------------------------
// Pack weights into transposed bf16 B matrices: Bt[n][k], n = conv*64 + o.
// ---------------------------------------------------------------------------
__global__ void pack_x_kernel(const float* __restrict__ Wa,
                              const float* __restrict__ Wb,
                              const float* __restrict__ Wc,
                              unsigned short* __restrict__ B1t)
{
    int gid = blockIdx.x * 256 + threadIdx.x;
    if (gid >= 192 * (KK_ * CIN_)) return;
    int n  = gid / (KK_ * CIN_);
    int kk = gid % (KK_ * CIN_);
    int conv = n >> 6, o = n & 63;
    const float* W = (conv == 0) ? Wa : ((conv == 1) ? Wb : Wc);
    B1t[gid] = f2bf(W[(size_t)kk * 64 + o]);
}

__global__ void pack_h_kernel(const float* __restrict__ Wa,
                              const float* __restrict__ Wb,
                              unsigned short* __restrict__ B2t)
{
    int gid = blockIdx.x * 256 + threadIdx.x;
    if (gid >= 128 * (KK_ * CHID_)) return;
    int n  = gid / (KK_ * CHID_);
    int kk = gid % (KK_ * CHID_);
    int conv = n >> 6, o = n & 63;
    const float* W = (conv == 0) ? Wa : Wb;
    B2t[gid] = f2bf(W[(size_t)kk * 64 + o]);
}

// ---------------------------------------------------------------------------
// MFMA bf16 GEMM, split-K, VGPR-prefetch staging. NO ATOMICS: each chunk
// writes its fp32 partial tile P[chunk][m][n] with plain coalesced stores
// (atomic RMW = full HBM line write-through on MI355X; measured 134 MB
// WRITE and 122 us in R6). Epilogue sums chunks.
// ---------------------------------------------------------------------------
template<int NT, int SPC>
__global__ __launch_bounds__(256) void mfma_gemm(
    const unsigned short* __restrict__ A, const unsigned short* __restrict__ Bt,
    float* __restrict__ P, int M, int Kd)
{
    constexpr int NFRAG = NT / 16;
    constexpr int BLD   = NT / 64;
    __shared__ unsigned short As[64][40];
    __shared__ unsigned short Bs[NT][40];

    using bf16x8 = __attribute__((ext_vector_type(8))) short;
    using f32x4  = __attribute__((ext_vector_type(4))) float;

    const int tid  = threadIdx.x;
    const int wave = tid >> 6;
    const int lane = tid & 63;
    const int quad = lane >> 4;
    const int l16  = lane & 15;
    const int m0   = blockIdx.x * 64;
    const int chunk = blockIdx.y;

    const int steps = Kd >> 5;
    const int s0 = chunk * SPC;
    const int s1 = min(steps, s0 + SPC);

    f32x4 acc[NFRAG];
#pragma unroll
    for (int f = 0; f < NFRAG; ++f) acc[f] = (f32x4){0.f, 0.f, 0.f, 0.f};

    const int  arow   = tid >> 2;
    const int  acol   = (tid & 3) * 8;
    const bool avalid = (m0 + arow) < M;
    const unsigned short* Aptr = A + (size_t)(avalid ? (m0 + arow) : 0) * Kd + acol;

    uint4 a_st = make_uint4(0u, 0u, 0u, 0u);
    uint4 b_st[BLD];
    if (avalid) a_st = *(const uint4*)(Aptr + (s0 << 5));
#pragma unroll
    for (int j = 0; j < BLD; ++j) {
        int u = tid + 256 * j;
        b_st[j] = *(const uint4*)(Bt + (size_t)(u >> 2) * Kd + (s0 << 5) + (u & 3) * 8);
    }

    for (int s = s0; s < s1; ++s) {
        __syncthreads();
        *(uint4*)&As[arow][acol] = a_st;
#pragma unroll
        for (int j = 0; j < BLD; ++j) {
            int u = tid + 256 * j;
            *(uint4*)&Bs[u >> 2][(u & 3) * 8] = b_st[j];
        }
        __syncthreads();
        if (s + 1 < s1) {
            if (avalid) a_st = *(const uint4*)(Aptr + ((s + 1) << 5));
#pragma unroll
            for (int j = 0; j < BLD; ++j) {
                int u = tid + 256 * j;
                b_st[j] = *(const uint4*)(Bt + (size_t)(u >> 2) * Kd + ((s + 1) << 5) + (u & 3) * 8);
            }
        }
        bf16x8 af = *(bf16x8*)&As[wave * 16 + l16][quad * 8];
#pragma unroll
        for (int f = 0; f < NFRAG; ++f) {
            bf16x8 bfv = *(bf16x8*)&Bs[f * 16 + l16][quad * 8];
            acc[f] = __builtin_amdgcn_mfma_f32_16x16x32_bf16(af, bfv, acc[f], 0, 0, 0);
        }
    }

    // plain coalesced stores of the fp32 partial tile (M%16==0 -> mb guard ok)
    const int mb = m0 + wave * 16 + quad * 4;
    if (mb < M) {
        float* Pc = P + (size_t)chunk * M * NT;
#pragma unroll
        for (int f = 0; f < NFRAG; ++f) {
            const int n = f * 16 + l16;
#pragma unroll
            for (int r = 0; r < 4; ++r)
                Pc[(size_t)(mb + r) * NT + n] = acc[f][r];
        }
    }
}

// ---------------------------------------------------------------------------
// Epilogue: one wave per node, lane = output channel. Sums split-K partials,
// mean-agg (deg from offs), root GEMV (x/h rows staged in wave-private LDS),
// GRU gates, coalesced out write.
// ---------------------------------------------------------------------------
__global__ __launch_bounds__(256) void epilogue_kernel(
    const float* __restrict__ P1, const float* __restrict__ P2,
    const int* __restrict__ offs,
    const float* __restrict__ x, const float* __restrict__ hidden,
    const float* __restrict__ root_xr, const float* __restrict__ root_hr,
    const float* __restrict__ root_xz, const float* __restrict__ root_hz,
    const float* __restrict__ root_xn,
    const float* __restrict__ b_xr, const float* __restrict__ b_hr,
    const float* __restrict__ b_xz, const float* __restrict__ b_hz,
    const float* __restrict__ b_xn,
    float* __restrict__ out)
{
    __shared__ float xsh[4][32];
    __shared__ float hsh[4][64];
    const int w = threadIdx.x >> 6;
    const int o = threadIdx.x & 63;
    const int m = blockIdx.x * 4 + w;
    if (m >= NN_) return;

    if (o < 32) xsh[w][o] = x[(size_t)m * 32 + o];
    const float hval = hidden[(size_t)m * 64 + o];
    hsh[w][o] = hval;

    float axr = 0.f, axz = 0.f, axn = 0.f;
#pragma unroll
    for (int c = 0; c < CH1_; ++c) {
        const float* p = P1 + ((size_t)c * NN_ + m) * 192;
        axr += p[o]; axz += p[64 + o]; axn += p[128 + o];
    }
    float ahr = 0.f, ahz = 0.f;
#pragma unroll
    for (int c = 0; c < CH2_; ++c) {
        const float* p = P2 + ((size_t)c * NN_ + m) * 128;
        ahr += p[o]; ahz += p[64 + o];
    }

    const int   dg   = offs[m + 1] - offs[m];
    const float dinv = 1.0f / fmaxf((float)dg, 1.0f);
    axr *= dinv; axz *= dinv; axn *= dinv; ahr *= dinv; ahz *= dinv;

    float sxr = 0.f, sxz = 0.f, sxn = 0.f;
#pragma unroll
    for (int c = 0; c < CIN_; ++c) {
        float xv = xsh[w][c];
        sxr += xv * root_xr[c * 64 + o];
        sxz += xv * root_xz[c * 64 + o];
        sxn += xv * root_xn[c * 64 + o];
    }
    float shr = 0.f, shz = 0.f;
#pragma unroll
    for (int c = 0; c < CHID_; ++c) {
        float hv = hsh[w][c];
        shr += hv * root_hr[c * 64 + o];
        shz += hv * root_hz[c * 64 + o];
    }

    const float conv_xr = axr + sxr + b_xr[o];
    const float conv_xz = axz + sxz + b_xz[o];
    const float conv_xn = axn + sxn + b_xn[o];
    const float hr_out  = ahr + shr + b_hr[o];
    const float conv_hz = ahz + shz + b_hz[o];

    const float rg = 1.0f / (1.0f + expf(-(conv_xr + hr_out)));
    const float zg = 1.0f / (1.0f + expf(-(conv_xz + conv_hz)));
    const float ng = tanhf(conv_xn + rg * hr_out);
    out[(size_t)m * 64 + o] = (1.0f - zg) * ng + zg * hval;
}

// ---------------------------------------------------------------------------
extern "C" void kernel_launch(void* const* d_in, const int* in_sizes, int n_in,
                              void* d_out, int out_size, void* d_ws, size_t ws_size,
                              hipStream_t stream)
{
    const float* x       = (const float*)d_in[0];
    const float* hidden  = (const float*)d_in[1];
    const int*   ei      = (const int*)  d_in[2];
    const float* attr    = (const float*)d_in[3];
    const float* W_xr    = (const float*)d_in[4];
    const float* root_xr = (const float*)d_in[5];
    const float* b_xr    = (const float*)d_in[6];
    const float* W_hr    = (const float*)d_in[7];
    const float* root_hr = (const float*)d_in[8];
    const float* b_hr    = (const float*)d_in[9];
    const float* W_xz    = (const float*)d_in[10];
    const float* root_xz = (const float*)d_in[11];
    const float* b_xz    = (const float*)d_in[12];
    const float* W_hz    = (const float*)d_in[13];
    const float* root_hz = (const float*)d_in[14];
    const float* b_hz    = (const float*)d_in[15];
    const float* W_xn    = (const float*)d_in[16];
    const float* root_xn = (const float*)d_in[17];
    const float* b_xn    = (const float*)d_in[18];
    // d_in[19..21] (W_hn/root_hn/b_hn) are dead: reference reuses hr_out.
    float* out = (float*)d_out;

    // Workspace (~204 MB)
    char* w = (char*)d_ws;
    unsigned short* Tx  = (unsigned short*)w; w += (size_t)NN_ * KK_ * CIN_  * 2;  // 48 MB
    unsigned short* Th  = (unsigned short*)w; w += (size_t)NN_ * KK_ * CHID_ * 2;  // 96 MB
    unsigned short* B1t = (unsigned short*)w; w += (size_t)192 * KK_ * CIN_  * 2;  // 1.5 MB
    unsigned short* B2t = (unsigned short*)w; w += (size_t)128 * KK_ * CHID_ * 2;  // 2.0 MB
    float* P1   = (float*)w; w += (size_t)CH1_ * NN_ * 192 * 4;                    // 36.9 MB
    float* P2   = (float*)w; w += (size_t)CH2_ * NN_ * 128 * 4;                    // 18.4 MB
    int* deg    = (int*)w;   w += (size_t)NN_ * 4;
    int* offs   = (int*)w;   w += (size_t)(NN_ + 4) * 4;
    int* cursor = (int*)w;   w += (size_t)NN_ * 4;
    int* perm   = (int*)w;   w += (size_t)EE_ * 4;

    const int MT = (NN_ + 63) / 64;   // 94 m-tiles

    hipMemsetAsync(deg, 0, (size_t)NN_ * 4, stream);

    // ---- bucket edges by dst ----
    count_deg_kernel<<<(EE_ + 255) / 256, 256, 0, stream>>>(ei, deg);
    scan_kernel<<<1, 1024, 0, stream>>>(deg, offs, cursor);
    fill_perm_kernel<<<(EE_ + 255) / 256, 256, 0, stream>>>(ei, cursor, perm);

    // ---- weight packs ----
    pack_x_kernel<<<(192 * KK_ * CIN_ + 255) / 256, 256, 0, stream>>>(W_xr, W_xz, W_xn, B1t);
    pack_h_kernel<<<(128 * KK_ * CHID_ + 255) / 256, 256, 0, stream>>>(W_hr, W_hz, B2t);

    // ---- non-atomic LDS T builds ----
    build_T_kernel<CIN_><<<NN_, 256, 0, stream>>>(ei, attr, x, offs, perm, Tx);
    build_T_kernel<CHID_><<<NN_, 256, 0, stream>>>(ei, attr, hidden, offs, perm, Th);

    // ---- GEMMs -> fp32 partials, no atomics ----
    mfma_gemm<192, 16><<<dim3(MT, CH1_), 256, 0, stream>>>(Tx, B1t, P1, NN_, KK_ * CIN_);
    mfma_gemm<128, 42><<<dim3(MT, CH2_), 256, 0, stream>>>(Th, B2t, P2, NN_, KK_ * CHID_);

    // ---- fused reduce + GRU epilogue (wave per node) ----
    epilogue_kernel<<<(NN_ + 3) / 4, 256, 0, stream>>>(
        P1, P2, offs, x, hidden,
        root_xr, root_hr, root_xz, root_hz, root_xn,
        b_xr, b_hr, b_xz, b_hz, b_xn, out);
}